// Round 6
// baseline (880.375 us; speedup 1.0000x reference)
//
#include <hip/hip_runtime.h>
#include <hip/hip_bf16.h>

// B=32, T=2048, D=256, H=256, CS=32, N=8, G=4H+2N=1040.
// Scan over BATCH axis (32 steps), carry (T,H). Backward dir = col-reversed W_ih.
#define B_  32
#define T_  2048
#define D_  256
#define H_  256
#define G_  1040

#define NSL 8      // e-slices of width 32 (slice s == cumsoftmax chunk n)
#define NRB 16     // row-blocks of 128 rows (xs/hs image granularity)
#define NMB 4      // m-subblocks of 32 rows inside a rowblock
#define NKB 32     // K16 chunks over K=512
#define NF  5      // B col-frags: og,cg,ig,fg + [cols 0..15 | zero-pad]

using bf16   = __hip_bfloat16;
using short8 = __attribute__((ext_vector_type(8))) short;
using f32x16 = __attribute__((ext_vector_type(16))) float;

__device__ inline float sigmoidf_(float v) { return 1.f / (1.f + __expf(-v)); }
__device__ inline float tanh_(float v) {
  v = fminf(fmaxf(v, -15.f), 15.f);
  float e = __expf(2.f * v);
  return (e - 1.f) / (e + 1.f);
}
__device__ inline float bf2f(unsigned short u) {
  union { unsigned int i; float f; } c; c.i = ((unsigned int)u) << 16; return c.f;
}
__device__ inline float ldF(const void* p, size_t i, int isf) {
  return isf ? ((const float*)p)[i] : bf2f(((const unsigned short*)p)[i]);
}
__device__ inline short f2bs(float v) {
  bf16 h = __float2bfloat16(v);
  return *(short*)&h;
}

// meta: [0]=is_fp32, [8+b]=seq_len[b], [40+b]=row base[b]
__global__ __launch_bounds__(256) void detect_prep(
    const unsigned short* __restrict__ xh, const int* __restrict__ sli,
    int* __restrict__ meta)
{
  __shared__ int s_bad;
  if (threadIdx.x == 0) s_bad = 0;
  __syncthreads();
  int bad = 0;
  for (int i = threadIdx.x; i < 1024; i += 256) {
    float f = bf2f(xh[i]);
    if (!(fabsf(f) < 100.f)) bad = 1;
  }
  if (bad) atomicOr(&s_bad, 1);
  __syncthreads();
  if (threadIdx.x == 0) {
    meta[0] = s_bad;
    bool is64 = true;
    for (int i = 1; i < 32; i += 2) if (sli[i] != 0) is64 = false;
    int base = 0;
    for (int b = 0; b < B_; ++b) {
      int v = is64 ? sli[2 * b] : sli[b];
      meta[8 + b]  = v;
      meta[40 + b] = base;
      base += v;
    }
  }
}

__global__ __launch_bounds__(256) void build_bsum(
    const void* __restrict__ b_ih, const void* __restrict__ b_hh,
    float* __restrict__ bsum, const int* __restrict__ meta)
{
  const int isf = meta[0];
  int i = blockIdx.x * 256 + threadIdx.x;
  if (i < G_) bsum[i] = ldF(b_ih, i, isf) + ldF(b_hh, i, isf);
}

// xs[b][rb16][kbx16][mb4][lane64][8]: A-frag image for 32x32x16.
// lane -> (m=lane&31, k8=lane>>5); element (t = rb*128+mb*32+m, k = kbx*16+k8*8+j).
// Coalesced rebuild: block = (b, rb, mb) = 32 contiguous rows x 256 k (tile is
// CONTIGUOUS in x). Read coalesced -> LDS (stride 258 shorts, odd-dword = conflict-free)
// -> coalesced frag-image writes.
__global__ __launch_bounds__(256) void build_xs(
    const void* __restrict__ x, bf16* __restrict__ xs,
    const int* __restrict__ meta)
{
  __shared__ __align__(16) short tile[32 * 258];
  const int isf = meta[0];
  const int tid = threadIdx.x;
  const int mb  = blockIdx.x & 3;
  const int rb  = (blockIdx.x >> 2) & 15;
  const int b   = blockIdx.x >> 6;
  const int t0  = rb * 128 + mb * 32;
  const size_t base = ((size_t)b * T_ + t0) * D_;   // 8192 contiguous elements

  if (isf) {
    const float* src = (const float*)x + base;
    #pragma unroll
    for (int j = 0; j < 8; ++j) {
      const int idx = j * 1024 + tid * 4;
      float4 v = *(const float4*)(src + idx);
      const int r = idx >> 8, c = idx & 255;
      short* dst = &tile[r * 258 + c];
      dst[0] = f2bs(v.x); dst[1] = f2bs(v.y); dst[2] = f2bs(v.z); dst[3] = f2bs(v.w);
    }
  } else {
    const short* src = (const short*)x + base;
    #pragma unroll
    for (int j = 0; j < 4; ++j) {
      const int idx = j * 2048 + tid * 8;
      short8 v = *(const short8*)(src + idx);
      *(short8*)&tile[(idx >> 8) * 258 + (idx & 255)] = v;
    }
  }
  __syncthreads();

  bf16* dstB = xs + (((size_t)b * NRB + rb) * 16) * (NMB * 512) + (size_t)mb * 512;
  #pragma unroll
  for (int it = 0; it < 4; ++it) {
    const int chunk = it * 256 + tid;      // (kbx, lane)
    const int kbx  = chunk >> 6;
    const int lane = chunk & 63;
    const int m  = lane & 31;
    const int k0 = kbx * 16 + (lane >> 5) * 8;
    short8 v = *(const short8*)&tile[m * 258 + k0];
    *(short8*)(dstB + (size_t)kbx * (NMB * 512) + lane * 8) = v;
  }
}

// Wsw[d][s][kb32][f5][lane64][8]: B-frag image. lane -> (n=lane&31, k8=lane>>5);
// gate col: f<4 -> 16+f*256+s*32+n ; f==4 -> (n<16 ? n : zero). k<256 -> W_ih
// (dir1 col-reversed), else W_hh.
__global__ __launch_bounds__(256) void build_wsw(
    const void* __restrict__ W_ih, const void* __restrict__ W_hh,
    bf16* __restrict__ Wsw, const int* __restrict__ meta)
{
  const int isf = meta[0];
  int idx = blockIdx.x * 256 + threadIdx.x;   // over 2*8*32*5*64
  if (idx >= 2 * NSL * NKB * NF * 64) return;
  const int lane = idx & 63;
  const int f    = (idx >> 6) % NF;
  const int kb   = (idx / (64 * NF)) % NKB;
  const int sl   = (idx / (64 * NF * NKB)) % NSL;
  const int d    = idx / (64 * NF * NKB * NSL);
  const int n    = lane & 31;
  const int k0   = kb * 16 + (lane >> 5) * 8;
  const int g = (f < 4) ? (16 + f * H_ + sl * 32 + n) : ((n < 16) ? n : -1);
  short8 v;
  #pragma unroll
  for (int j = 0; j < 8; ++j) {
    float val = 0.f;
    const int k = k0 + j;
    if (g >= 0)
      val = (k < D_) ? ldF(W_ih, (size_t)g * D_ + (d ? (D_ - 1 - k) : k), isf)
                     : ldF(W_hh, (size_t)g * H_ + (k - D_), isf);
    v[j] = f2bs(val);
  }
  *(short8*)(Wsw + (size_t)idx * 8) = v;
}

// ---------------------------------------------------------------------------
// Fused step. Grid (s=8, rbp=64, d=2) — blockIdx.x = slice so linear%8 = s
// (XCD affinity: each XCD streams one 0.33 MB W slice). Block = 256 thr = 4
// waves over the SAME 32 rows, 4-way K-split (w<2: x half via xs, w>=2: h half
// via hs). No LDS/barriers in the K-loop — W and A frags load straight from
// their global frag images (coalesced 1 KB/wave). LDS tree-reduce, then cell
// math spread over all 256 threads.
// ---------------------------------------------------------------------------
__global__ __launch_bounds__(256) void step_fused(
    const bf16* __restrict__ xs, const bf16* __restrict__ Wsw,
    bf16* __restrict__ hs, float* __restrict__ cs,
    const float* __restrict__ bsum, void* __restrict__ out,
    const int* __restrict__ meta, int b)
{
  __shared__ float red[2][NF][16][64];   // 40 KB; red[1] reused as gall, red[0] as gsm
  __shared__ float csm[32][2];

  const int tid   = threadIdx.x;
  const int lane  = tid & 63;
  const int w     = tid >> 6;
  const int s     = blockIdx.x;
  const int rbp   = blockIdx.y;          // 0..63 (32-row block)
  const int d     = blockIdx.z;
  const int rb    = rbp >> 2, mb = rbp & 3;
  const int col   = lane & 31;
  const int khalf = lane >> 5;

  const int isf    = meta[0];
  const int len_s  = meta[8 + b];
  const int base_s = meta[40 + b];

  f32x16 acc[NF];
  #pragma unroll
  for (int f = 0; f < NF; ++f)
    #pragma unroll
    for (int r = 0; r < 16; ++r) acc[f][r] = 0.f;

  const bf16* aBase = (w < 2)
      ? xs + ((((size_t)b * NRB + rb) * 16 + w * 8) * NMB + mb) * 512 + lane * 8
      : hs + ((((size_t)d * NRB + rb) * 16 + (w - 2) * 8) * NMB + mb) * 512 + lane * 8;
  const bf16* wBase = Wsw + ((((size_t)d * NSL + s) * NKB + w * 8) * NF) * 512 + lane * 8;

  #pragma unroll
  for (int i = 0; i < 8; ++i) {
    short8 af = *(const short8*)(aBase + (size_t)i * (NMB * 512));
    #pragma unroll
    for (int f = 0; f < NF; ++f) {
      short8 bfr = *(const short8*)(wBase + (size_t)i * (NF * 512) + f * 512);
      acc[f] = __builtin_amdgcn_mfma_f32_32x32x16_bf16(af, bfr, acc[f], 0, 0, 0);
    }
  }

  // ---- cross-wave K reduction: w1->red[0], w3->red[1]; w0+=red[0], w2+=red[1];
  //      w2->red[0]; w0+=red[0]. ----
  if (w & 1) {
    float* dst = &red[w >> 1][0][0][0];
    #pragma unroll
    for (int f = 0; f < NF; ++f)
      #pragma unroll
      for (int r = 0; r < 16; ++r) dst[(f * 16 + r) * 64 + lane] = acc[f][r];
  }
  __syncthreads();
  if (!(w & 1)) {
    const float* srcp = &red[w >> 1][0][0][0];
    #pragma unroll
    for (int f = 0; f < NF; ++f)
      #pragma unroll
      for (int r = 0; r < 16; ++r) acc[f][r] += srcp[(f * 16 + r) * 64 + lane];
  }
  __syncthreads();
  if (w == 2) {
    float* dst = &red[0][0][0][0];
    #pragma unroll
    for (int f = 0; f < NF; ++f)
      #pragma unroll
      for (int r = 0; r < 16; ++r) dst[(f * 16 + r) * 64 + lane] = acc[f][r];
  }
  __syncthreads();

  float* gall = &red[1][0][0][0];        // [4][16][64] raw og,cg,ig,fg
  float* gsm  = &red[0][0][0][0];        // [32][17] cumsoftmax cols (biased)
  if (w == 0) {
    const float* srcp = &red[0][0][0][0];
    #pragma unroll
    for (int f = 0; f < NF; ++f)
      #pragma unroll
      for (int r = 0; r < 16; ++r) acc[f][r] += srcp[(f * 16 + r) * 64 + lane];
    // write redistributed gates (reads above complete before same-wave writes)
    #pragma unroll
    for (int f = 0; f < 4; ++f)
      #pragma unroll
      for (int r = 0; r < 16; ++r) gall[(f * 16 + r) * 64 + lane] = acc[f][r];
    if (col < 16) {
      const float c0b = bsum[col];
      #pragma unroll
      for (int r = 0; r < 16; ++r) {
        const int row = (r & 3) + 8 * (r >> 2) + 4 * khalf;   // 32x32 C layout
        gsm[row * 17 + col] = acc[4][r] + c0b;
      }
    }
  }
  __syncthreads();

  if (tid < 32) {
    const int row = tid;
    float g[16];
    #pragma unroll
    for (int i = 0; i < 16; ++i) g[i] = gsm[row * 17 + i];
    float m1 = g[0], m2 = g[8];
    #pragma unroll
    for (int i = 1; i < 8; ++i) { m1 = fmaxf(m1, g[i]); m2 = fmaxf(m2, g[8 + i]); }
    float S1 = 0.f, P1 = 0.f, S2 = 0.f, P2 = 0.f;
    #pragma unroll
    for (int i = 0; i < 8; ++i) {
      float e1 = __expf(g[i] - m1);     S1 += e1; if (i <= s) P1 += e1;
      float e2 = __expf(g[8 + i] - m2); S2 += e2; if (i <= s) P2 += e2;
    }
    csm[row][0] = 1.f - P1 / S1;
    csm[row][1] = P2 / S2;
  }
  __syncthreads();

  // ---- cell math: 256 threads x 4 elements of the 32x32 (row, col) tile ----
  const int cc   = tid & 31;             // element col within slice
  const int row0 = (tid >> 5) * 4;
  const int e    = s * 32 + cc;          // h index
  const int kbh  = e >> 4, k8e = (e >> 3) & 1, ele = e & 7;

  float bg[4];
  #pragma unroll
  for (int f = 0; f < 4; ++f) bg[f] = bsum[16 + f * H_ + e];

  float* csSlab = cs + ((((size_t)d * NSL + s) * NRB + rb) * NMB + mb) * 1024;
  bf16*  hsBase = hs + ((((size_t)d * NRB + rb) * 16 + kbh) * NMB + mb) * 512;

  #pragma unroll
  for (int rr = 0; rr < 4; ++rr) {
    const int row = row0 + rr;
    const int kh    = (row >> 2) & 1;
    const int rA    = (row & 3) + ((row >> 3) << 2);
    const int laneF = cc + 32 * kh;
    const float cin = csm[row][0];
    const float cfg = csm[row][1];
    const float og = sigmoidf_(gall[(0 * 16 + rA) * 64 + laneF] + bg[0]);
    const float cg = tanh_   (gall[(1 * 16 + rA) * 64 + laneF] + bg[1]);
    const float ig = sigmoidf_(gall[(2 * 16 + rA) * 64 + laneF] + bg[2]);
    const float fg = sigmoidf_(gall[(3 * 16 + rA) * 64 + laneF] + bg[3]);
    const float ov = cfg * cin;
    const float f2 = fg * ov + (cfg - ov);
    const float i2 = ig * ov + (cin - ov);
    const float cprev = csSlab[rA * 64 + laneF];
    const float cy = f2 * cprev + i2 * cg;
    csSlab[rA * 64 + laneF] = cy;
    const float hy = og * tanh_(cy);
    hsBase[(size_t)(row + 32 * k8e) * 8 + ele] = __float2bfloat16(hy);
    const int t = rbp * 32 + row;
    if (t < len_s) {
      const size_t o = (size_t)(base_s + t) * (2 * H_) + (size_t)d * H_ + e;
      if (isf) ((float*)out)[o] = hy;
      else     ((bf16*)out)[o]  = __float2bfloat16(hy);
    }
  }
}

// ---------------------------------------------------------------------------
extern "C" void kernel_launch(void* const* d_in, const int* in_sizes, int n_in,
                              void* d_out, int out_size, void* d_ws, size_t ws_size,
                              hipStream_t stream)
{
  const void* x    = d_in[0];
  const int*  sl   = (const int*)d_in[1];
  const void* W_ih = d_in[2];
  const void* b_ih = d_in[3];
  const void* W_hh = d_in[4];
  const void* b_hh = d_in[5];

  char* ws = (char*)d_ws;
  size_t off = 0;
  auto alloc = [&](size_t bytes) {
    void* p = ws + off;
    off = (off + bytes + 255) & ~(size_t)255;
    return p;
  };
  int*   meta = (int*)  alloc(128 * sizeof(int));
  bf16*  xs   = (bf16*) alloc((size_t)B_ * T_ * D_ * sizeof(bf16));            // 32 MB
  bf16*  Wsw  = (bf16*) alloc((size_t)2 * NSL * NKB * NF * 512 * sizeof(bf16)); // 2.6 MB
  bf16*  hs   = (bf16*) alloc((size_t)2 * T_ * H_ * sizeof(bf16));             // 2 MB
  float* cs   = (float*)alloc((size_t)2 * T_ * H_ * sizeof(float));            // 4 MB
  float* bsum = (float*)alloc((size_t)G_ * sizeof(float));

  hipMemsetAsync(hs, 0, (size_t)2 * T_ * H_ * sizeof(bf16), stream);
  hipMemsetAsync(cs, 0, (size_t)2 * T_ * H_ * sizeof(float), stream);

  detect_prep<<<1, 256, 0, stream>>>((const unsigned short*)x, sl, meta);
  build_bsum<<<(G_ + 255) / 256, 256, 0, stream>>>(b_ih, b_hh, bsum, meta);
  build_xs<<<B_ * NRB * NMB, 256, 0, stream>>>(x, xs, meta);
  build_wsw<<<(2 * NSL * NKB * NF * 64 + 255) / 256, 256, 0, stream>>>(W_ih, W_hh, Wsw, meta);

  for (int b = 0; b < B_; ++b)
    step_fused<<<dim3(NSL, 64, 2), 256, 0, stream>>>(xs, Wsw, hs, cs, bsum, d_out, meta, b);
}